// Round 4
// baseline (85.104 us; speedup 1.0000x reference)
//
#include <hip/hip_runtime.h>
#include <hip/hip_bf16.h>

// GaussianVoxelizer: B=1, G=128 gaussians, F=16 features, N=100*100*8=80000.
// Sum/count formulation (== reference's incremental masked mean).
//
// R4 design: gaussian-centric scatter. Only ~20% of gaussians intersect the
// z-slab [-1,5.4] and each maha<=4 ellipsoid covers only ~10^2 voxels, so
// voxel-centric O(N*G) evaluation wastes >99% of its work. Per gaussian:
// voxel AABB from the exact ellipsoid support bound r_i = 2*sqrt(cov_ii)
// (widened by 1 voxel via floor/ceil -> can never exclude a true hit),
// iterate box, atomicAdd {cnt, dens, 16 feats} on hit. Voxel centers are
// recomputed as (i+0.5)*0.8+lo -- bit-identical to the reference grid.
//
// Inputs (setup_inputs order):
//   d_in[0] grid_coords (N,3) f32   (unused -- recomputed exactly)
//   d_in[1] means3d     (1,G,3) f32
//   d_in[2] opacities   (1,G,1) f32
//   d_in[3] features    (1,G,F) f32
//   d_in[4] covariances (1,G,3,3) f32
// Output: dens (N) f32 followed by feats (N,F) f32, concatenated flat.

#define GV_F 16
#define GV_SX 100
#define GV_SY 100
#define GV_SZ 8
#define GV_LOX (-40.0f)
#define GV_LOY (-40.0f)
#define GV_LOZ (-1.0f)
#define GV_VOX 0.8f

// Zero the accumulators: d_out (17*N floats) and cnt (N floats in ws).
__global__ __launch_bounds__(256)
void gv_zero(float4* __restrict__ out4, int n_out4,
             float4* __restrict__ cnt4, int n_cnt4)
{
    const int i = blockIdx.x * blockDim.x + threadIdx.x;
    const int stride = gridDim.x * blockDim.x;
    const float4 z = make_float4(0.f, 0.f, 0.f, 0.f);
    for (int j = i; j < n_out4; j += stride) out4[j] = z;
    for (int j = i; j < n_cnt4; j += stride) cnt4[j] = z;
}

// One block per gaussian; lanes stride over the gaussian's voxel AABB.
__global__ __launch_bounds__(256)
void gv_accum(const float* __restrict__ means,  // (G,3)
              const float* __restrict__ opac,   // (G)
              const float* __restrict__ feats,  // (G,F)
              const float* __restrict__ covs,   // (G,9)
              float* __restrict__ cnt,          // (N)
              float* __restrict__ out_dens,     // (N)
              float* __restrict__ out_feat,     // (N,F)
              int G)
{
    const int g = blockIdx.x;
    if (g >= G) return;

    // Redundant per-thread setup (same addresses -> cache broadcast).
    const float mx = means[g * 3 + 0];
    const float my = means[g * 3 + 1];
    const float mz = means[g * 3 + 2];
    const float c00 = covs[g * 9 + 0];
    const float c01 = covs[g * 9 + 1];
    const float c02 = covs[g * 9 + 2];
    const float c11 = covs[g * 9 + 4];
    const float c12 = covs[g * 9 + 5];
    const float c22 = covs[g * 9 + 8];

    // AABB of {maha<=4}: half-width along axis i is exactly 2*sqrt(cov_ii).
    const float rx = 2.0f * sqrtf(c00);
    const float ry = 2.0f * sqrtf(c11);
    const float rz = 2.0f * sqrtf(c22);
    // center(i) = (i+0.5)*VOX + lo ; floor/ceil widen by <=1 voxel (safe).
    const int ix0 = max(0,         (int)floorf((mx - rx - GV_LOX) / GV_VOX - 0.5f));
    const int ix1 = min(GV_SX - 1, (int)ceilf ((mx + rx - GV_LOX) / GV_VOX - 0.5f));
    const int iy0 = max(0,         (int)floorf((my - ry - GV_LOY) / GV_VOX - 0.5f));
    const int iy1 = min(GV_SY - 1, (int)ceilf ((my + ry - GV_LOY) / GV_VOX - 0.5f));
    const int iz0 = max(0,         (int)floorf((mz - rz - GV_LOZ) / GV_VOX - 0.5f));
    const int iz1 = min(GV_SZ - 1, (int)ceilf ((mz + rz - GV_LOZ) / GV_VOX - 0.5f));
    if (ix0 > ix1 || iy0 > iy1 || iz0 > iz1) return;   // ~80% of gaussians exit here

    // Inverse covariance via adjugate (cov = A*A^T + 0.1I is SPD, det>=1e-3);
    // fold the -0.5 of exp(-0.5*maha) and pre-double the off-diagonals.
    const float m00 = c11 * c22 - c12 * c12;
    const float m01 = c02 * c12 - c01 * c22;
    const float m02 = c01 * c12 - c02 * c11;
    const float det = c00 * m00 + c01 * m01 + c02 * m02;
    const float s = -0.5f / det;
    const float k00 = m00 * s;
    const float k01 = m01 * (2.0f * s);
    const float k02 = m02 * (2.0f * s);
    const float k11 = (c00 * c22 - c02 * c02) * s;
    const float k12 = (c01 * c02 - c00 * c12) * (2.0f * s);
    const float k22 = (c00 * c11 - c01 * c01) * s;

    const float op = opac[g];
    float fo_w[GV_F];
    #pragma unroll
    for (int j = 0; j < GV_F; ++j) fo_w[j] = op * feats[g * GV_F + j];

    const int nx = ix1 - ix0 + 1;
    const int ny = iy1 - iy0 + 1;
    const int nz = iz1 - iz0 + 1;
    const int nyz = ny * nz;
    const int total = nx * nyz;

    for (int idx = threadIdx.x; idx < total; idx += 256) {
        int ix = idx / nyz;
        int rem = idx - ix * nyz;
        int iy = rem / nz;
        int iz = rem - iy * nz;
        ix += ix0; iy += iy0; iz += iz0;

        const float cx = ((float)ix + 0.5f) * GV_VOX + GV_LOX;
        const float cy = ((float)iy + 0.5f) * GV_VOX + GV_LOY;
        const float cz = ((float)iz + 0.5f) * GV_VOX + GV_LOZ;
        const float dx = cx - mx;
        const float dy = cy - my;
        const float dz = cz - mz;
        // tt = -0.5 * maha
        float a = k00 * dx;
        a = fmaf(k01, dy, a);
        a = fmaf(k02, dz, a);
        float tt = a * dx;
        float b = k11 * dy;
        b = fmaf(k12, dz, b);
        tt = fmaf(b, dy, tt);
        tt = fmaf(k22 * dz, dz, tt);

        if (tt >= -2.0f) {                       // maha <= 4
            const float w = __expf(tt);
            const int n = (ix * GV_SY + iy) * GV_SZ + iz;
            atomicAdd(&cnt[n], 1.0f);
            atomicAdd(&out_dens[n], op * w);
            float* fp = out_feat + (size_t)n * GV_F;
            #pragma unroll
            for (int j = 0; j < GV_F; ++j) atomicAdd(&fp[j], fo_w[j] * w);
        }
    }
}

// Divide sums by counts.
__global__ __launch_bounds__(256)
void gv_final(const float* __restrict__ cnt,
              float* __restrict__ out_dens,
              float* __restrict__ out_feat,
              int N)
{
    const int n = blockIdx.x * blockDim.x + threadIdx.x;
    if (n >= N) return;
    const float c = cnt[n];
    const float inv = (c > 0.0f) ? (1.0f / c) : 0.0f;
    out_dens[n] *= inv;
    float4* fo = (float4*)(out_feat + (size_t)n * GV_F);
    #pragma unroll
    for (int q = 0; q < 4; ++q) {
        float4 v = fo[q];
        v.x *= inv; v.y *= inv; v.z *= inv; v.w *= inv;
        fo[q] = v;
    }
}

extern "C" void kernel_launch(void* const* d_in, const int* in_sizes, int n_in,
                              void* d_out, int out_size, void* d_ws, size_t ws_size,
                              hipStream_t stream) {
    const float* means = (const float*)d_in[1];
    const float* opac  = (const float*)d_in[2];
    const float* feats = (const float*)d_in[3];
    const float* covs  = (const float*)d_in[4];

    const int N = in_sizes[0] / 3;       // 80000
    const int G = in_sizes[2];           // B*G = 128 (B=1)

    float* cnt      = (float*)d_ws;          // (N) accumulator counts
    float* out_dens = (float*)d_out;         // (N)
    float* out_feat = (float*)d_out + N;     // (N,F)

    const int n_out4 = (N * (GV_F + 1)) / 4; // 17N floats, N%4==0
    const int n_cnt4 = N / 4;
    const int zgrid = (n_out4 + 255) / 256;  // one pass, cnt loop is a 2nd iter for low blocks
    gv_zero<<<zgrid, 256, 0, stream>>>((float4*)d_out, n_out4, (float4*)cnt, n_cnt4);

    gv_accum<<<G, 256, 0, stream>>>(means, opac, feats, covs,
                                    cnt, out_dens, out_feat, G);

    gv_final<<<(N + 255) / 256, 256, 0, stream>>>(cnt, out_dens, out_feat, N);
}

// Round 5
// 66.408 us; speedup vs baseline: 1.2815x; 1.2815x over previous
//
#include <hip/hip_runtime.h>
#include <hip/hip_bf16.h>

// GaussianVoxelizer: B=1, G=128 gaussians, F=16 features, N=100*100*8=80000.
// Sum/count formulation (== reference's incremental masked mean).
//
// R5 design: single-launch gather with per-block gaussian culling.
//  - 313 blocks x 256 threads, one voxel per thread (n = (ix*100+iy)*8+iz).
//  - Setup: threads 0..127 stage gaussian params (mean, opacity,
//    -0.5*inv_cov with off-diags pre-doubled, opacity*features) into LDS and
//    test the gaussian's exact AABB (half-width 2*sqrt(cov_ii) + eps, the
//    support bound of {maha<=4}) against the block's voxel-center AABB.
//  - Deterministic ballot+popcount compaction -> short list (avg ~1-2).
//  - Eval loop over list only; LDS reads are wave-uniform broadcasts.
//  - No grid read (centers recomputed as (i+0.5)*0.8+lo, bit-identical to
//    the reference grid), no atomics, no extra passes, coalesced stores.
//
// Inputs (setup_inputs order):
//   d_in[0] grid_coords (N,3) f32   (unused -- recomputed exactly)
//   d_in[1] means3d     (1,G,3) f32
//   d_in[2] opacities   (1,G,1) f32
//   d_in[3] features    (1,G,F) f32
//   d_in[4] covariances (1,G,3,3) f32
// Output: dens (N) f32 followed by feats (N,F) f32, concatenated flat.

#define GV_F 16
#define GV_SX 100
#define GV_SY 100
#define GV_SZ 8
#define GV_SYZ (GV_SY * GV_SZ)   // 800
#define GV_LOX (-40.0f)
#define GV_LOY (-40.0f)
#define GV_LOZ (-1.0f)
#define GV_VOX 0.8f
#define GV_GMAX 128

__global__ __launch_bounds__(256)
void GaussianVoxelizer_40467181863368_kernel(
    const float* __restrict__ means,  // (G,3)
    const float* __restrict__ opac,   // (G)
    const float* __restrict__ feats,  // (G,F)
    const float* __restrict__ covs,   // (G,9)
    float* __restrict__ out_dens,     // (N)
    float* __restrict__ out_feat,     // (N,F)
    int N, int G)
{
    // packed params: [0..2]=mean, [3]=opacity, [4..9]=k00,k01,k02,k11,k12,k22
    __shared__ float s_p[GV_GMAX][10];
    __shared__ float s_f[GV_GMAX][GV_F];         // opacity * features
    __shared__ unsigned long long s_mask[2];
    __shared__ int s_list[GV_GMAX];

    const int t = threadIdx.x;
    const int n0 = blockIdx.x * 256;
    const int nlast = min(n0 + 255, N - 1);

    // ---- Block AABB over voxel CENTERS ----
    const int ix_lo = n0 / GV_SYZ;
    const int ix_hi = nlast / GV_SYZ;
    const float bx0 = ((float)ix_lo + 0.5f) * GV_VOX + GV_LOX;
    const float bx1 = ((float)ix_hi + 0.5f) * GV_VOX + GV_LOX;
    float by0, by1;
    if (ix_lo == ix_hi) {
        const int iy0b = (n0 - ix_lo * GV_SYZ) >> 3;          // /GV_SZ
        const int iy1b = (nlast - ix_hi * GV_SYZ) >> 3;
        by0 = ((float)iy0b + 0.5f) * GV_VOX + GV_LOY;
        by1 = ((float)iy1b + 0.5f) * GV_VOX + GV_LOY;
    } else {                                                   // straddles an x boundary
        by0 = 0.5f * GV_VOX + GV_LOY;
        by1 = ((float)(GV_SY - 1) + 0.5f) * GV_VOX + GV_LOY;
    }
    const float bz0 = 0.5f * GV_VOX + GV_LOZ;                  // -0.6
    const float bz1 = ((float)(GV_SZ - 1) + 0.5f) * GV_VOX + GV_LOZ;  // 5.0

    // ---- Stage + cull (threads 0..G-1, G<=128) ----
    bool flag = false;
    if (t < G) {
        const float mx = means[t * 3 + 0];
        const float my = means[t * 3 + 1];
        const float mz = means[t * 3 + 2];
        const float c00 = covs[t * 9 + 0];
        const float c01 = covs[t * 9 + 1];
        const float c02 = covs[t * 9 + 2];
        const float c11 = covs[t * 9 + 4];
        const float c12 = covs[t * 9 + 5];
        const float c22 = covs[t * 9 + 8];

        // exact support bound of {maha<=4} + fp-safety pad
        const float rx = 2.0f * sqrtf(c00) + 1e-3f;
        const float ry = 2.0f * sqrtf(c11) + 1e-3f;
        const float rz = 2.0f * sqrtf(c22) + 1e-3f;
        flag = (mx - rx <= bx1) && (mx + rx >= bx0) &&
               (my - ry <= by1) && (my + ry >= by0) &&
               (mz - rz <= bz1) && (mz + rz >= bz0);

        // inverse covariance via adjugate (cov = A*A^T + 0.1I, SPD, det>=1e-3);
        // fold exp's -0.5 and pre-double off-diagonals.
        const float m00 = c11 * c22 - c12 * c12;
        const float m01 = c02 * c12 - c01 * c22;
        const float m02 = c01 * c12 - c02 * c11;
        const float det = c00 * m00 + c01 * m01 + c02 * m02;
        const float s = -0.5f / det;
        const float op = opac[t];

        s_p[t][0] = mx;
        s_p[t][1] = my;
        s_p[t][2] = mz;
        s_p[t][3] = op;
        s_p[t][4] = m00 * s;
        s_p[t][5] = m01 * (2.0f * s);
        s_p[t][6] = m02 * (2.0f * s);
        s_p[t][7] = (c00 * c22 - c02 * c02) * s;
        s_p[t][8] = (c01 * c02 - c00 * c12) * (2.0f * s);
        s_p[t][9] = (c00 * c11 - c01 * c01) * s;
        #pragma unroll
        for (int j = 0; j < GV_F; ++j) s_f[t][j] = op * feats[t * GV_F + j];
    }

    // ---- Deterministic compaction (ascending g) ----
    const unsigned long long m = __ballot(flag);
    if ((t & 63) == 0 && (t >> 6) < 2) s_mask[t >> 6] = m;
    if (G <= 64 && t == 64) s_mask[1] = 0;   // safety if G fits one wave
    __syncthreads();
    if (flag) {
        const int w = t >> 6;
        const unsigned long long lt = (t & 63) ? ((1ull << (t & 63)) - 1ull) : 0ull;
        const int pos = (w == 0) ? __popcll(s_mask[0] & lt)
                                 : __popcll(s_mask[0]) + __popcll(s_mask[1] & lt);
        s_list[pos] = t;
    }
    __syncthreads();
    const int L = __popcll(s_mask[0]) + __popcll(s_mask[1]);

    // ---- Per-voxel evaluation over the short list ----
    const int n = n0 + t;
    if (n >= N) return;

    const int ix = n / GV_SYZ;
    const int rem = n - ix * GV_SYZ;
    const int iy = rem >> 3;
    const int iz = rem & 7;
    const float cx = ((float)ix + 0.5f) * GV_VOX + GV_LOX;
    const float cy = ((float)iy + 0.5f) * GV_VOX + GV_LOY;
    const float cz = ((float)iz + 0.5f) * GV_VOX + GV_LOZ;

    float cnt = 0.0f;
    float sum_d = 0.0f;
    float sum_f[GV_F];
    #pragma unroll
    for (int j = 0; j < GV_F; ++j) sum_f[j] = 0.0f;

    for (int l = 0; l < L; ++l) {
        const int g = s_list[l];                // block-uniform -> LDS broadcast
        const float dx = cx - s_p[g][0];
        const float dy = cy - s_p[g][1];
        const float dz = cz - s_p[g][2];
        // tt = -0.5 * maha
        float a = s_p[g][4] * dx;
        a = fmaf(s_p[g][5], dy, a);
        a = fmaf(s_p[g][6], dz, a);
        float tt = a * dx;
        float b = s_p[g][7] * dy;
        b = fmaf(s_p[g][8], dz, b);
        tt = fmaf(b, dy, tt);
        tt = fmaf(s_p[g][9] * dz, dz, tt);
        if (tt >= -2.0f) {                      // maha <= 4
            const float w = __expf(tt);
            cnt += 1.0f;
            sum_d = fmaf(s_p[g][3], w, sum_d);
            #pragma unroll
            for (int j = 0; j < GV_F; ++j) sum_f[j] = fmaf(s_f[g][j], w, sum_f[j]);
        }
    }

    const float inv_c = (cnt > 0.0f) ? (1.0f / cnt) : 0.0f;
    out_dens[n] = sum_d * inv_c;
    float4* fo = (float4*)(out_feat + (size_t)n * GV_F);
    #pragma unroll
    for (int q = 0; q < 4; ++q) {
        fo[q] = make_float4(sum_f[4 * q + 0] * inv_c,
                            sum_f[4 * q + 1] * inv_c,
                            sum_f[4 * q + 2] * inv_c,
                            sum_f[4 * q + 3] * inv_c);
    }
}

extern "C" void kernel_launch(void* const* d_in, const int* in_sizes, int n_in,
                              void* d_out, int out_size, void* d_ws, size_t ws_size,
                              hipStream_t stream) {
    const float* means = (const float*)d_in[1];
    const float* opac  = (const float*)d_in[2];
    const float* feats = (const float*)d_in[3];
    const float* covs  = (const float*)d_in[4];

    const int N = in_sizes[0] / 3;       // 80000
    const int G = in_sizes[2];           // B*G = 128 (B=1)

    float* out_dens = (float*)d_out;         // (N)
    float* out_feat = (float*)d_out + N;     // (N,F)

    const int grid_n = (N + 255) / 256;      // 313 blocks
    GaussianVoxelizer_40467181863368_kernel<<<grid_n, 256, 0, stream>>>(
        means, opac, feats, covs, out_dens, out_feat, N, G);
}

// Round 6
// 65.248 us; speedup vs baseline: 1.3043x; 1.0178x over previous
//
#include <hip/hip_runtime.h>
#include <hip/hip_bf16.h>

// GaussianVoxelizer: B=1, G=128 gaussians, F=16 features, N=100*100*8=80000.
// Sum/count formulation (== reference's incremental masked mean).
//
// R6 design: R5's single-launch gather + per-block cull, but with
// SURVIVOR-ONLY staging. Cull reads only mean+cov (L1/L2-hot). Only the
// ~L (avg ~1) gaussians whose AABB (half-width 2*sqrt(cov_ii)+eps, the
// exact support bound of {maha<=4}) overlaps the block's voxel-center AABB
// pay for: opacity load, 3x3 inverse (adjugate, -0.5 folded, off-diags
// pre-doubled), float4 feature loads, LDS writes -- written directly at the
// compacted slot (deterministic ascending-g via ballot prefix-popcount).
// Eval loop runs over the L compacted slots; LDS broadcast reads; no
// atomics; no extra passes; unconditional coalesced stores.
//
// Inputs (setup_inputs order):
//   d_in[0] grid_coords (N,3) f32   (unused -- centers recomputed as
//                                    (i+0.5)*0.8+lo, bit-identical to ref)
//   d_in[1] means3d     (1,G,3) f32
//   d_in[2] opacities   (1,G,1) f32
//   d_in[3] features    (1,G,F) f32
//   d_in[4] covariances (1,G,3,3) f32
// Output: dens (N) f32 followed by feats (N,F) f32, concatenated flat.

#define GV_F 16
#define GV_SX 100
#define GV_SY 100
#define GV_SZ 8
#define GV_SYZ (GV_SY * GV_SZ)   // 800
#define GV_LOX (-40.0f)
#define GV_LOY (-40.0f)
#define GV_LOZ (-1.0f)
#define GV_VOX 0.8f
#define GV_GMAX 128

__global__ __launch_bounds__(256)
void GaussianVoxelizer_40467181863368_kernel(
    const float* __restrict__ means,  // (G,3)
    const float* __restrict__ opac,   // (G)
    const float* __restrict__ feats,  // (G,F)
    const float* __restrict__ covs,   // (G,9)
    float* __restrict__ out_dens,     // (N)
    float* __restrict__ out_feat,     // (N,F)
    int N, int G)
{
    // compacted survivor params: [0..2]=mean, [3]=opacity,
    // [4..9]=k00,k01,k02,k11,k12,k22 (coeffs of -0.5*maha, off-diags doubled)
    __shared__ float s_p[GV_GMAX][10];
    __shared__ float s_f[GV_GMAX][GV_F];   // opacity * features (compacted)
    __shared__ unsigned long long s_mask[4];

    const int t = threadIdx.x;
    const int wv = t >> 6;
    const int n0 = blockIdx.x * 256;
    const int nlast = min(n0 + 255, N - 1);

    // ---- Block AABB over voxel CENTERS ----
    const int ix_lo = n0 / GV_SYZ;
    const int ix_hi = nlast / GV_SYZ;
    const float bx0 = ((float)ix_lo + 0.5f) * GV_VOX + GV_LOX;
    const float bx1 = ((float)ix_hi + 0.5f) * GV_VOX + GV_LOX;
    float by0, by1;
    if (ix_lo == ix_hi) {
        const int iy0b = (n0 - ix_lo * GV_SYZ) >> 3;          // /GV_SZ
        const int iy1b = (nlast - ix_hi * GV_SYZ) >> 3;
        by0 = ((float)iy0b + 0.5f) * GV_VOX + GV_LOY;
        by1 = ((float)iy1b + 0.5f) * GV_VOX + GV_LOY;
    } else {                                                   // straddles x boundary
        by0 = 0.5f * GV_VOX + GV_LOY;
        by1 = ((float)(GV_SY - 1) + 0.5f) * GV_VOX + GV_LOY;
    }
    const float bz0 = 0.5f * GV_VOX + GV_LOZ;                  // -0.6
    const float bz1 = ((float)(GV_SZ - 1) + 0.5f) * GV_VOX + GV_LOZ;  // 5.0

    // ---- Cull: mean + cov only (same 6 KB read by every block -> L2-hot) ----
    bool flag = false;
    float mx = 0.f, my = 0.f, mz = 0.f;
    float c00 = 0.f, c01 = 0.f, c02 = 0.f, c11 = 0.f, c12 = 0.f, c22 = 0.f;
    if (t < G) {
        mx = means[t * 3 + 0];
        my = means[t * 3 + 1];
        mz = means[t * 3 + 2];
        c00 = covs[t * 9 + 0];
        c01 = covs[t * 9 + 1];
        c02 = covs[t * 9 + 2];
        c11 = covs[t * 9 + 4];
        c12 = covs[t * 9 + 5];
        c22 = covs[t * 9 + 8];
        const float rx = 2.0f * sqrtf(c00) + 1e-3f;   // support bound + fp pad
        const float ry = 2.0f * sqrtf(c11) + 1e-3f;
        const float rz = 2.0f * sqrtf(c22) + 1e-3f;
        flag = (mx - rx <= bx1) && (mx + rx >= bx0) &&
               (my - ry <= by1) && (my + ry >= by0) &&
               (mz - rz <= bz1) && (mz + rz >= bz0);
    }

    const unsigned long long m = __ballot(flag);
    if ((t & 63) == 0) s_mask[wv] = m;
    __syncthreads();

    // ---- Survivor-only staging into compacted slots (ascending g) ----
    if (flag) {
        int pos = 0;
        #pragma unroll
        for (int i = 0; i < 4; ++i) pos += (i < wv) ? __popcll(s_mask[i]) : 0;
        const unsigned long long lt = (t & 63) ? ((1ull << (t & 63)) - 1ull) : 0ull;
        pos += __popcll(m & lt);

        // inverse covariance via adjugate (cov = A*A^T + 0.1I, SPD, det>=1e-3)
        const float m00 = c11 * c22 - c12 * c12;
        const float m01 = c02 * c12 - c01 * c22;
        const float m02 = c01 * c12 - c02 * c11;
        const float det = c00 * m00 + c01 * m01 + c02 * m02;
        const float s = -0.5f / det;
        const float op = opac[t];

        s_p[pos][0] = mx;
        s_p[pos][1] = my;
        s_p[pos][2] = mz;
        s_p[pos][3] = op;
        s_p[pos][4] = m00 * s;
        s_p[pos][5] = m01 * (2.0f * s);
        s_p[pos][6] = m02 * (2.0f * s);
        s_p[pos][7] = (c00 * c22 - c02 * c02) * s;
        s_p[pos][8] = (c01 * c02 - c00 * c12) * (2.0f * s);
        s_p[pos][9] = (c00 * c11 - c01 * c01) * s;

        const float4* fr = (const float4*)(feats + (size_t)t * GV_F);
        float4* fw = (float4*)(&s_f[pos][0]);
        #pragma unroll
        for (int q = 0; q < 4; ++q) {
            float4 v = fr[q];
            v.x *= op; v.y *= op; v.z *= op; v.w *= op;
            fw[q] = v;
        }
    }
    __syncthreads();
    const int L = __popcll(s_mask[0]) + __popcll(s_mask[1]) +
                  __popcll(s_mask[2]) + __popcll(s_mask[3]);

    // ---- Per-voxel evaluation over the compacted list ----
    const int n = n0 + t;
    if (n >= N) return;

    const int ix = n / GV_SYZ;
    const int rem = n - ix * GV_SYZ;
    const int iy = rem >> 3;
    const int iz = rem & 7;
    const float cx = ((float)ix + 0.5f) * GV_VOX + GV_LOX;
    const float cy = ((float)iy + 0.5f) * GV_VOX + GV_LOY;
    const float cz = ((float)iz + 0.5f) * GV_VOX + GV_LOZ;

    float cnt = 0.0f;
    float sum_d = 0.0f;
    float sum_f[GV_F];
    #pragma unroll
    for (int j = 0; j < GV_F; ++j) sum_f[j] = 0.0f;

    for (int l = 0; l < L; ++l) {               // l block-uniform -> LDS broadcast
        const float dx = cx - s_p[l][0];
        const float dy = cy - s_p[l][1];
        const float dz = cz - s_p[l][2];
        // tt = -0.5 * maha
        float a = s_p[l][4] * dx;
        a = fmaf(s_p[l][5], dy, a);
        a = fmaf(s_p[l][6], dz, a);
        float tt = a * dx;
        float b = s_p[l][7] * dy;
        b = fmaf(s_p[l][8], dz, b);
        tt = fmaf(b, dy, tt);
        tt = fmaf(s_p[l][9] * dz, dz, tt);
        if (tt >= -2.0f) {                      // maha <= 4
            const float w = __expf(tt);
            cnt += 1.0f;
            sum_d = fmaf(s_p[l][3], w, sum_d);
            #pragma unroll
            for (int j = 0; j < GV_F; ++j) sum_f[j] = fmaf(s_f[l][j], w, sum_f[j]);
        }
    }

    const float inv_c = (cnt > 0.0f) ? (1.0f / cnt) : 0.0f;
    out_dens[n] = sum_d * inv_c;
    float4* fo = (float4*)(out_feat + (size_t)n * GV_F);
    #pragma unroll
    for (int q = 0; q < 4; ++q) {
        fo[q] = make_float4(sum_f[4 * q + 0] * inv_c,
                            sum_f[4 * q + 1] * inv_c,
                            sum_f[4 * q + 2] * inv_c,
                            sum_f[4 * q + 3] * inv_c);
    }
}

extern "C" void kernel_launch(void* const* d_in, const int* in_sizes, int n_in,
                              void* d_out, int out_size, void* d_ws, size_t ws_size,
                              hipStream_t stream) {
    const float* means = (const float*)d_in[1];
    const float* opac  = (const float*)d_in[2];
    const float* feats = (const float*)d_in[3];
    const float* covs  = (const float*)d_in[4];

    const int N = in_sizes[0] / 3;       // 80000
    const int G = in_sizes[2];           // B*G = 128 (B=1)

    float* out_dens = (float*)d_out;         // (N)
    float* out_feat = (float*)d_out + N;     // (N,F)

    const int grid_n = (N + 255) / 256;      // 313 blocks
    GaussianVoxelizer_40467181863368_kernel<<<grid_n, 256, 0, stream>>>(
        means, opac, feats, covs, out_dens, out_feat, N, G);
}